// Round 6
// baseline (451.935 us; speedup 1.0000x reference)
//
#include <hip/hip_runtime.h>
#include <math.h>

#define B_SZ   2048
#define F_SZ   12288
#define D_SZ   512
#define N_LK   100000
#define N_PAD  100096
#define NT2    782          // N_PAD / 128
#define NGRP   64           // persistent groups along nt (1024 blocks = 16 mt x 64 grp)

typedef __attribute__((ext_vector_type(8))) short bf16x8;
typedef __attribute__((ext_vector_type(8))) unsigned short ushort8;
typedef __attribute__((ext_vector_type(4))) float f32x4;

__device__ __forceinline__ unsigned short f2bf(float f) {
  union { float f; unsigned u; } v; v.f = f;
  unsigned r = v.u + 0x7FFFu + ((v.u >> 16) & 1u);
  return (unsigned short)(r >> 16);
}
__device__ __forceinline__ float bf2f(unsigned short h) {
  union { unsigned u; float f; } v; v.u = ((unsigned)h) << 16;
  return v.f;
}

#define GLOAD16(gp, lp) __builtin_amdgcn_global_load_lds( \
    (__attribute__((address_space(1))) void*)(gp),        \
    (__attribute__((address_space(3))) void*)(lp), 16, 0, 0)

#define VMCNT(n) asm volatile("s_waitcnt vmcnt(" #n ")" ::: "memory")

// ---------------- merged prep: conv_mse | transpose_w | conv_lookup | zero embf ----------
// Four independent memory-bound stages dispatched by block range (uniform per block).
#define PREP_MSE_BLKS   2048
#define PREP_TW_BLKS    1536   // 192 x 8 tiles of 64x64
#define PREP_LK_BLKS    (N_PAD / 4)
#define PREP_ZERO_BLKS  512
#define PREP_TOTAL (PREP_MSE_BLKS + PREP_TW_BLKS + PREP_LK_BLKS + PREP_ZERO_BLKS)

__global__ __launch_bounds__(256) void prep_k(
    const float* __restrict__ x, const float* __restrict__ y,
    unsigned short* __restrict__ xb, float* __restrict__ part,
    const float* __restrict__ W, unsigned short* __restrict__ Wt,
    const float* __restrict__ lk, unsigned short* __restrict__ lb,
    float* __restrict__ lsq, float* __restrict__ embf) {
  __shared__ float tl[64][65];
  const int bx = blockIdx.x;
  const int tid = threadIdx.x;

  if (bx < PREP_MSE_BLKS) {
    // ---- x->bf16 + mse partial ----
    const long n8 = (long)B_SZ * F_SZ / 8;
    long i = (long)bx * 256 + tid;
    const long stride = (long)PREP_MSE_BLKS * 256;
    float s = 0.f;
    for (; i < n8; i += stride) {
      const float4* px = (const float4*)(x + i * 8);
      const float4* py = (const float4*)(y + i * 8);
      float4 a = px[0], b = px[1];
      float4 c = py[0], d = py[1];
      ushort8 o;
      o[0] = f2bf(a.x); o[1] = f2bf(a.y); o[2] = f2bf(a.z); o[3] = f2bf(a.w);
      o[4] = f2bf(b.x); o[5] = f2bf(b.y); o[6] = f2bf(b.z); o[7] = f2bf(b.w);
      *(ushort8*)(xb + i * 8) = o;
      float t0 = a.x - c.x, t1 = a.y - c.y, t2 = a.z - c.z, t3 = a.w - c.w;
      float t4 = b.x - d.x, t5 = b.y - d.y, t6 = b.z - d.z, t7 = b.w - d.w;
      s += t0 * t0 + t1 * t1 + t2 * t2 + t3 * t3;
      s += t4 * t4 + t5 * t5 + t6 * t6 + t7 * t7;
    }
#pragma unroll
    for (int off = 1; off < 64; off <<= 1) s += __shfl_xor(s, off);
    if ((tid & 63) == 0) tl[0][tid >> 6] = s;
    __syncthreads();
    if (tid == 0) part[bx] = tl[0][0] + tl[0][1] + tl[0][2] + tl[0][3];
  } else if (bx < PREP_MSE_BLKS + PREP_TW_BLKS) {
    // ---- W [F,D] f32 -> Wt [D,F] bf16 ----
    const int b = bx - PREP_MSE_BLKS;
    const int r0 = (b % 192) * 64;  // F dim
    const int c0 = (b / 192) * 64;  // D dim
#pragma unroll
    for (int p = 0; p < 16; ++p) {
      int idx = p * 256 + tid;
      int r = idx >> 6, c = idx & 63;
      tl[c][r] = W[(size_t)(r0 + r) * D_SZ + c0 + c];
    }
    __syncthreads();
#pragma unroll
    for (int p = 0; p < 2; ++p) {
      int chunk = p * 256 + tid;
      int rr = chunk >> 3, cc = (chunk & 7) * 8;
      ushort8 o;
#pragma unroll
      for (int j = 0; j < 8; ++j) o[j] = f2bf(tl[rr][cc + j]);
      *(ushort8*)&Wt[(size_t)(c0 + rr) * F_SZ + r0 + cc] = o;
    }
  } else if (bx < PREP_MSE_BLKS + PREP_TW_BLKS + PREP_LK_BLKS) {
    // ---- lookup f32 -> bf16 (padded) + per-row sumsq ----
    const int n = (bx - PREP_MSE_BLKS - PREP_TW_BLKS) * 4 + (tid >> 6);
    const int t = tid & 63;
    ushort8 o;
    float s = 0.f;
    if (n < N_LK) {
      const float4* row = (const float4*)(lk + (size_t)n * D_SZ);
      float4 a = row[t * 2], b = row[t * 2 + 1];
      float v[8] = {a.x, a.y, a.z, a.w, b.x, b.y, b.z, b.w};
#pragma unroll
      for (int j = 0; j < 8; ++j) {
        o[j] = f2bf(v[j]);
        float q = bf2f(o[j]);
        s += q * q;
      }
    } else {
#pragma unroll
      for (int j = 0; j < 8; ++j) o[j] = 0;
    }
    *(ushort8*)&lb[(size_t)n * D_SZ + t * 8] = o;
#pragma unroll
    for (int off = 1; off < 64; off <<= 1) s += __shfl_xor(s, off);
    if (t == 0) lsq[n] = (n < N_LK) ? s : 1e30f;
  } else {
    // ---- zero embf (2048*512 f32 = 262144 float4) ----
    long i = (long)(bx - PREP_MSE_BLKS - PREP_TW_BLKS - PREP_LK_BLKS) * 256 + tid;
    const long n4 = (long)B_SZ * D_SZ / 4;
    const long stride = (long)PREP_ZERO_BLKS * 256;
    float4 z = {0.f, 0.f, 0.f, 0.f};
    for (; i < n4; i += stride) ((float4*)embf)[i] = z;
  }
}

// ---------------- GEMM-A split-K=12: embf(f32) += xb[128-tile] @ Wt^T[128-tile] ----------------
// grid 768 = mt(16) x dt(4) x ks(12); K-slice 1024 (32 steps), 3 blocks/CU.
// atomicAdd f32 epilogue (12 writers/address; output is hinge-clamped so rounding
// order is harmless).
__global__ __launch_bounds__(256) void gemm_a_sk(const unsigned short* __restrict__ A,
                                                 const unsigned short* __restrict__ Bm,
                                                 float* __restrict__ embf) {
  __shared__ unsigned short lsA[128 * 32];
  __shared__ unsigned short lsB[128 * 32];
  const int tid = threadIdx.x;
  const int bid = blockIdx.x;
  const int mt = bid & 15, dt = (bid >> 4) & 3, ks = bid >> 6;
  const int m0 = mt * 128, n0 = dt * 128;
  const int k0base = ks * 1024;
  const int l = tid & 63;
  const int w = tid >> 6;
  const int wr = (w >> 1) * 64, wc = (w & 1) * 64;
  const int g = l >> 4, lane16 = l & 15;

  const int srow = tid >> 2;
  const int scol = (tid & 3) * 8;
  const unsigned short* Ag0 = A + (size_t)(m0 + srow) * F_SZ + scol + k0base;
  const unsigned short* Ag1 = A + (size_t)(m0 + 64 + srow) * F_SZ + scol + k0base;
  const unsigned short* Bg0 = Bm + (size_t)(n0 + srow) * F_SZ + scol + k0base;
  const unsigned short* Bg1 = Bm + (size_t)(n0 + 64 + srow) * F_SZ + scol + k0base;
  unsigned short* la0 = &lsA[tid * 8];
  unsigned short* la1 = &lsA[2048 + tid * 8];
  unsigned short* lb0 = &lsB[tid * 8];
  unsigned short* lb1 = &lsB[2048 + tid * 8];

  int ar[4], br[4];
#pragma unroll
  for (int m = 0; m < 4; ++m) ar[m] = (wr + m * 16 + lane16) * 32 + g * 8;
#pragma unroll
  for (int n = 0; n < 4; ++n) br[n] = (wc + n * 16 + lane16) * 32 + g * 8;

  f32x4 acc[4][4] = {};

  for (int k0 = 0; k0 < 1024; k0 += 32) {
    GLOAD16(Ag0 + k0, la0);
    GLOAD16(Ag1 + k0, la1);
    GLOAD16(Bg0 + k0, lb0);
    GLOAD16(Bg1 + k0, lb1);
    __syncthreads();
    bf16x8 af[4], bfv[4];
#pragma unroll
    for (int m = 0; m < 4; ++m) af[m] = *(const bf16x8*)&lsA[ar[m]];
#pragma unroll
    for (int n = 0; n < 4; ++n) bfv[n] = *(const bf16x8*)&lsB[br[n]];
#pragma unroll
    for (int m = 0; m < 4; ++m)
#pragma unroll
      for (int n = 0; n < 4; ++n)
        acc[m][n] = __builtin_amdgcn_mfma_f32_16x16x32_bf16(af[m], bfv[n], acc[m][n], 0, 0, 0);
    __syncthreads();
  }
#pragma unroll
  for (int m = 0; m < 4; ++m)
#pragma unroll
    for (int n = 0; n < 4; ++n)
#pragma unroll
      for (int r = 0; r < 4; ++r) {
        int row = m0 + wr + m * 16 + g * 4 + r;
        int col = n0 + wc + n * 16 + lane16;
        atomicAdd(&embf[(size_t)row * D_SZ + col], acc[m][n][r]);
      }
}

// embf f32 -> emb bf16 + per-row esq (of the bf16-rounded values)
__global__ __launch_bounds__(256) void esq_conv_k(const float* __restrict__ embf,
                                                  unsigned short* __restrict__ emb,
                                                  float* __restrict__ esq) {
  int r = blockIdx.x * 4 + (threadIdx.x >> 6);
  int t = threadIdx.x & 63;
  const float4* row = (const float4*)(embf + (size_t)r * D_SZ);
  float4 a = row[t * 2], b = row[t * 2 + 1];
  float v[8] = {a.x, a.y, a.z, a.w, b.x, b.y, b.z, b.w};
  ushort8 o;
  float s = 0.f;
#pragma unroll
  for (int j = 0; j < 8; ++j) {
    o[j] = f2bf(v[j]);
    float q = bf2f(o[j]);
    s += q * q;
  }
  *(ushort8*)&emb[(size_t)r * D_SZ + t * 8] = o;
#pragma unroll
  for (int off = 1; off < 64; off <<= 1) s += __shfl_xor(s, off);
  if (t == 0) esq[r] = s;
}

// ---------------- GEMM-B: persistent fused cdist-min, 128x128, 4 blocks/CU ----------------
// grid 1024 (4/CU), 256 threads (4 waves, 2x2; each wave 64x64 = acc[4][4]).
// mt = bid/64 (16 M-tiles of 128); grp = bid%64: the 16 blocks sharing a B-stream have
// bid == grp (mod 8) -> SAME XCD (64%8==0) and co-start -> B fetched once per XCD L2.
// 2-deep LDS ring (2 x (A 8KB + B 8KB) = 32KB), counted vmcnt(4): tiles t+1,t+2 in
// flight, never drained mid-loop. Loads retire in order and all threads issue identical
// load sequences -> counted wait + barrier race-free. No atomics: per-row min folded in
// registers across nt, one store per (grp,row).
__global__ __launch_bounds__(256, 4) void gemm_min_k(
    const unsigned short* __restrict__ A,   // emb [2048][512] bf16
    const unsigned short* __restrict__ Bm,  // lb  [100096][512] bf16
    const float* __restrict__ esq, const float* __restrict__ lsq,
    float* __restrict__ minpart) {          // [NGRP][2048]
  __shared__ unsigned short lsA[2 * 4096];
  __shared__ unsigned short lsB[2 * 4096];

  const int tid = threadIdx.x;
  const int grp = blockIdx.x % NGRP;
  const int mt = blockIdx.x / NGRP;    // 0..15
  const int m0 = mt * 128;
  const int J = (NT2 - grp + NGRP - 1) / NGRP;  // 12 or 13 nt-tiles
  const int T = J * 16;                         // total K-steps (K=512/BK=32 per tile)

  const int l = tid & 63;
  const int w = tid >> 6;
  const int wr = (w >> 1) * 64, wc = (w & 1) * 64;
  const int g = l >> 4, lane16 = l & 15;

  // staging: linear LDS dest; global source column slot pre-swizzled so ds_read's
  // slot' = slot ^ ((row>>1)&3) finds the right data (both-sides-or-neither rule).
  const int srow = tid >> 2;                       // 0..63
  const int sslot = (tid & 3) ^ ((tid >> 3) & 3);  // row parity block invariant mod 4
  const unsigned short* Ag0 = A + (size_t)(m0 + srow) * D_SZ + sslot * 8;
  const unsigned short* Ag1 = A + (size_t)(m0 + 64 + srow) * D_SZ + sslot * 8;
  const unsigned short* Bgs = Bm + (size_t)srow * D_SZ + sslot * 8;

  int ar[4], br[4];
#pragma unroll
  for (int m = 0; m < 4; ++m) {
    int row = wr + m * 16 + lane16;
    ar[m] = row * 32 + ((g ^ ((row >> 1) & 3)) * 8);
  }
#pragma unroll
  for (int n = 0; n < 4; ++n) {
    int row = wc + n * 16 + lane16;
    br[n] = row * 32 + ((g ^ ((row >> 1) & 3)) * 8);
  }

  f32x4 acc[4][4] = {};
  float rmin[4][4];
#pragma unroll
  for (int m = 0; m < 4; ++m)
#pragma unroll
    for (int r = 0; r < 4; ++r) rmin[m][r] = 3.0e38f;

  auto stage = [&](int s) {
    const int kt = (s & 15) * 32;
    const int b = s & 1;
    const size_t nrow = (size_t)(grp + NGRP * (s >> 4)) * 128 * D_SZ;
    GLOAD16(Ag0 + kt, &lsA[b * 4096 + tid * 8]);
    GLOAD16(Ag1 + kt, &lsA[b * 4096 + 2048 + tid * 8]);
    GLOAD16(Bgs + nrow + kt, &lsB[b * 4096 + tid * 8]);
    GLOAD16(Bgs + nrow + (size_t)64 * D_SZ + kt, &lsB[b * 4096 + 2048 + tid * 8]);
  };

  // prologue: tiles 0,1 in flight; retire tile 0
  stage(0); stage(1);
  VMCNT(4);
  __builtin_amdgcn_s_barrier();

  for (int t = 0; t < T; ++t) {
    const int b = t & 1;
    const unsigned short* pA = &lsA[b * 4096];
    const unsigned short* pB = &lsB[b * 4096];
    bf16x8 af[4], bfv[4];
#pragma unroll
    for (int n = 0; n < 4; ++n) bfv[n] = *(const bf16x8*)&pB[br[n]];
#pragma unroll
    for (int m = 0; m < 4; ++m) af[m] = *(const bf16x8*)&pA[ar[m]];
    asm volatile("s_waitcnt lgkmcnt(0)" ::: "memory");
    __builtin_amdgcn_sched_barrier(0);
    __builtin_amdgcn_s_barrier();            // all waves' reads done -> buf b reusable
    if (t + 2 < T) stage(t + 2);             // uniform branch
    __builtin_amdgcn_s_setprio(1);
#pragma unroll
    for (int m = 0; m < 4; ++m)
#pragma unroll
      for (int n = 0; n < 4; ++n)
        acc[m][n] = __builtin_amdgcn_mfma_f32_16x16x32_bf16(af[m], bfv[n], acc[m][n], 0, 0, 0);
    __builtin_amdgcn_s_setprio(0);
    if ((t & 15) == 15) {                    // nt-tile boundary: fold min, reset acc
      const int j = t >> 4;
      const int n0s = (grp + NGRP * j) * 128;
      float lsql[4];
#pragma unroll
      for (int n = 0; n < 4; ++n) lsql[n] = lsq[n0s + wc + n * 16 + lane16];
#pragma unroll
      for (int m = 0; m < 4; ++m)
#pragma unroll
        for (int r = 0; r < 4; ++r) {
          float v = fminf(fminf(lsql[0] - 2.0f * acc[m][0][r], lsql[1] - 2.0f * acc[m][1][r]),
                          fminf(lsql[2] - 2.0f * acc[m][2][r], lsql[3] - 2.0f * acc[m][3][r]));
          rmin[m][r] = fminf(rmin[m][r], v);
        }
#pragma unroll
      for (int m = 0; m < 4; ++m)
#pragma unroll
        for (int n = 0; n < 4; ++n) acc[m][n] = f32x4{0.f, 0.f, 0.f, 0.f};
    }
    if (t + 2 < T) { VMCNT(4); }             // retire tile t+1; t+2 in flight
    else if (t + 1 < T) { VMCNT(0); }        // retire final tile
    __builtin_amdgcn_s_barrier();            // publish tile t+1
  }

  // writeout: reduce rmin over the 16-lane col group, one store per (grp,row)
#pragma unroll
  for (int m = 0; m < 4; ++m)
#pragma unroll
    for (int r = 0; r < 4; ++r) {
      float best = rmin[m][r];
#pragma unroll
      for (int off = 1; off < 16; off <<= 1) best = fminf(best, __shfl_xor(best, off));
      if (lane16 == 0) {
        int row = m0 + wr + m * 16 + g * 4 + r;
        minpart[grp * B_SZ + row] = fmaxf(esq[row] + best, 0.0f);
      }
    }
}

// ---------------- final reductions ----------------

__global__ __launch_bounds__(256) void mse_final_k(const float* __restrict__ part,
                                                   float* __restrict__ msev,
                                                   int nparts, float inv_n) {
  float s = 0.f;
  for (int i = threadIdx.x; i < nparts; i += 256) s += part[i];
#pragma unroll
  for (int off = 1; off < 64; off <<= 1) s += __shfl_xor(s, off);
  __shared__ float sm[4];
  if ((threadIdx.x & 63) == 0) sm[threadIdx.x >> 6] = s;
  __syncthreads();
  if (threadIdx.x == 0) msev[0] = (sm[0] + sm[1] + sm[2] + sm[3]) * inv_n;
}

__global__ void finalize_k(const float* __restrict__ minpart,
                           const float* __restrict__ msev,
                           float* __restrict__ out, int n) {
  int i = blockIdx.x * blockDim.x + threadIdx.x;
  if (i < n) {
    float m = 3.0e38f;
#pragma unroll 8
    for (int gp = 0; gp < NGRP; ++gp) m = fminf(m, minpart[gp * B_SZ + i]);
    out[i] = msev[0] + fminf(50.0f - sqrtf(m), 0.0f) * 5.0f;
  }
}

// ---------------- launch ----------------

extern "C" void kernel_launch(void* const* d_in, const int* in_sizes, int n_in,
                              void* d_out, int out_size, void* d_ws, size_t ws_size,
                              hipStream_t stream) {
  const float* x  = (const float*)d_in[0];
  const float* y  = (const float*)d_in[1];
  const float* W  = (const float*)d_in[2];
  const float* lk = (const float*)d_in[3];
  float* out = (float*)d_out;

  char* ws = (char*)d_ws;
  size_t off = 0;
  auto alloc = [&](size_t bytes) -> void* {
    void* p = ws + off;
    off = (off + bytes + 255) & ~(size_t)255;
    return p;
  };
  unsigned short* xb  = (unsigned short*)alloc((size_t)B_SZ * F_SZ * 2);   // 50.3 MB
  unsigned short* Wt  = (unsigned short*)alloc((size_t)D_SZ * F_SZ * 2);   // 12.6 MB
  unsigned short* lb  = (unsigned short*)alloc((size_t)N_PAD * D_SZ * 2);  // 102.5 MB
  float* lsq          = (float*)alloc((size_t)N_PAD * 4);
  float* embf         = (float*)alloc((size_t)B_SZ * D_SZ * 4);            // 4 MB
  unsigned short* emb = (unsigned short*)alloc((size_t)B_SZ * D_SZ * 2);
  float* esq          = (float*)alloc((size_t)B_SZ * 4);
  float* minpart      = (float*)alloc((size_t)NGRP * B_SZ * 4);            // 512 KB
  float* msep         = (float*)alloc(2048 * 4);
  float* msev         = (float*)alloc(256);
  (void)ws_size; (void)in_sizes; (void)n_in; (void)out_size;

  // merged prep: x->bf16 + mse partials | W transpose | lookup conv+sumsq | zero embf
  prep_k<<<PREP_TOTAL, 256, 0, stream>>>(x, y, xb, msep, W, Wt, lk, lb, lsq, embf);

  // emb(f32) = xb @ Wt^T via split-K=12 atomicAdd (768 blocks, 3/CU)
  gemm_a_sk<<<768, 256, 0, stream>>>(xb, Wt, embf);
  esq_conv_k<<<B_SZ / 4, 256, 0, stream>>>(embf, emb, esq);

  // persistent fused cdist-min (no atomics), 1024 blocks, 4/CU
  gemm_min_k<<<1024, 256, 0, stream>>>(emb, lb, esq, lsq, minpart);

  mse_final_k<<<1, 256, 0, stream>>>(msep, msev, 2048, 1.0f / ((float)B_SZ * (float)F_SZ));
  finalize_k<<<(B_SZ + 255) / 256, 256, 0, stream>>>(minpart, msev, out, B_SZ);
}

// Round 7
// 429.014 us; speedup vs baseline: 1.0534x; 1.0534x over previous
//
#include <hip/hip_runtime.h>
#include <math.h>

#define B_SZ   2048
#define F_SZ   12288
#define D_SZ   512
#define N_LK   100000
#define N_PAD  100096
#define NTILES 391          // N_PAD / 256
#define NGRP   32           // persistent groups along nt (256 blocks = 8 mt x 32 grp)

typedef __attribute__((ext_vector_type(8))) short bf16x8;
typedef __attribute__((ext_vector_type(8))) unsigned short ushort8;
typedef __attribute__((ext_vector_type(4))) float f32x4;

__device__ __forceinline__ unsigned short f2bf(float f) {
  union { float f; unsigned u; } v; v.f = f;
  unsigned r = v.u + 0x7FFFu + ((v.u >> 16) & 1u);
  return (unsigned short)(r >> 16);
}
__device__ __forceinline__ float bf2f(unsigned short h) {
  union { unsigned u; float f; } v; v.u = ((unsigned)h) << 16;
  return v.f;
}

#define GLOAD16(gp, lp) __builtin_amdgcn_global_load_lds( \
    (__attribute__((address_space(1))) void*)(gp),        \
    (__attribute__((address_space(3))) void*)(lp), 16, 0, 0)

#define VMCNT(n) asm volatile("s_waitcnt vmcnt(" #n ")" ::: "memory")
#define BARRIER __builtin_amdgcn_s_barrier()
#define LGKM0 do { asm volatile("s_waitcnt lgkmcnt(0)" ::: "memory"); \
                   __builtin_amdgcn_sched_barrier(0); } while (0)

// ---------------- merged prep: conv_mse | transpose_w | conv_lookup | zero embf ----------
#define PREP_MSE_BLKS   2048
#define PREP_TW_BLKS    1536   // 192 x 8 tiles of 64x64
#define PREP_LK_BLKS    (N_PAD / 4)
#define PREP_ZERO_BLKS  512
#define PREP_TOTAL (PREP_MSE_BLKS + PREP_TW_BLKS + PREP_LK_BLKS + PREP_ZERO_BLKS)

__global__ __launch_bounds__(256) void prep_k(
    const float* __restrict__ x, const float* __restrict__ y,
    unsigned short* __restrict__ xb, float* __restrict__ part,
    const float* __restrict__ W, unsigned short* __restrict__ Wt,
    const float* __restrict__ lk, unsigned short* __restrict__ lb,
    float* __restrict__ lsq, float* __restrict__ embf) {
  __shared__ float tl[64][65];
  const int bx = blockIdx.x;
  const int tid = threadIdx.x;

  if (bx < PREP_MSE_BLKS) {
    const long n8 = (long)B_SZ * F_SZ / 8;
    long i = (long)bx * 256 + tid;
    const long stride = (long)PREP_MSE_BLKS * 256;
    float s = 0.f;
    for (; i < n8; i += stride) {
      const float4* px = (const float4*)(x + i * 8);
      const float4* py = (const float4*)(y + i * 8);
      float4 a = px[0], b = px[1];
      float4 c = py[0], d = py[1];
      ushort8 o;
      o[0] = f2bf(a.x); o[1] = f2bf(a.y); o[2] = f2bf(a.z); o[3] = f2bf(a.w);
      o[4] = f2bf(b.x); o[5] = f2bf(b.y); o[6] = f2bf(b.z); o[7] = f2bf(b.w);
      *(ushort8*)(xb + i * 8) = o;
      float t0 = a.x - c.x, t1 = a.y - c.y, t2 = a.z - c.z, t3 = a.w - c.w;
      float t4 = b.x - d.x, t5 = b.y - d.y, t6 = b.z - d.z, t7 = b.w - d.w;
      s += t0 * t0 + t1 * t1 + t2 * t2 + t3 * t3;
      s += t4 * t4 + t5 * t5 + t6 * t6 + t7 * t7;
    }
#pragma unroll
    for (int off = 1; off < 64; off <<= 1) s += __shfl_xor(s, off);
    if ((tid & 63) == 0) tl[0][tid >> 6] = s;
    __syncthreads();
    if (tid == 0) part[bx] = tl[0][0] + tl[0][1] + tl[0][2] + tl[0][3];
  } else if (bx < PREP_MSE_BLKS + PREP_TW_BLKS) {
    const int b = bx - PREP_MSE_BLKS;
    const int r0 = (b % 192) * 64;  // F dim
    const int c0 = (b / 192) * 64;  // D dim
#pragma unroll
    for (int p = 0; p < 16; ++p) {
      int idx = p * 256 + tid;
      int r = idx >> 6, c = idx & 63;
      tl[c][r] = W[(size_t)(r0 + r) * D_SZ + c0 + c];
    }
    __syncthreads();
#pragma unroll
    for (int p = 0; p < 2; ++p) {
      int chunk = p * 256 + tid;
      int rr = chunk >> 3, cc = (chunk & 7) * 8;
      ushort8 o;
#pragma unroll
      for (int j = 0; j < 8; ++j) o[j] = f2bf(tl[rr][cc + j]);
      *(ushort8*)&Wt[(size_t)(c0 + rr) * F_SZ + r0 + cc] = o;
    }
  } else if (bx < PREP_MSE_BLKS + PREP_TW_BLKS + PREP_LK_BLKS) {
    const int n = (bx - PREP_MSE_BLKS - PREP_TW_BLKS) * 4 + (tid >> 6);
    const int t = tid & 63;
    ushort8 o;
    float s = 0.f;
    if (n < N_LK) {
      const float4* row = (const float4*)(lk + (size_t)n * D_SZ);
      float4 a = row[t * 2], b = row[t * 2 + 1];
      float v[8] = {a.x, a.y, a.z, a.w, b.x, b.y, b.z, b.w};
#pragma unroll
      for (int j = 0; j < 8; ++j) {
        o[j] = f2bf(v[j]);
        float q = bf2f(o[j]);
        s += q * q;
      }
    } else {
#pragma unroll
      for (int j = 0; j < 8; ++j) o[j] = 0;
    }
    *(ushort8*)&lb[(size_t)n * D_SZ + t * 8] = o;
#pragma unroll
    for (int off = 1; off < 64; off <<= 1) s += __shfl_xor(s, off);
    if (t == 0) lsq[n] = (n < N_LK) ? s : 1e30f;
  } else {
    long i = (long)(bx - PREP_MSE_BLKS - PREP_TW_BLKS - PREP_LK_BLKS) * 256 + tid;
    const long n4 = (long)B_SZ * D_SZ / 4;
    const long stride = (long)PREP_ZERO_BLKS * 256;
    float4 z = {0.f, 0.f, 0.f, 0.f};
    for (; i < n4; i += stride) ((float4*)embf)[i] = z;
  }
}

// ---------------- GEMM-A split-K=12 ----------------
__global__ __launch_bounds__(256) void gemm_a_sk(const unsigned short* __restrict__ A,
                                                 const unsigned short* __restrict__ Bm,
                                                 float* __restrict__ embf) {
  __shared__ unsigned short lsA[128 * 32];
  __shared__ unsigned short lsB[128 * 32];
  const int tid = threadIdx.x;
  const int bid = blockIdx.x;
  const int mt = bid & 15, dt = (bid >> 4) & 3, ks = bid >> 6;
  const int m0 = mt * 128, n0 = dt * 128;
  const int k0base = ks * 1024;
  const int l = tid & 63;
  const int w = tid >> 6;
  const int wr = (w >> 1) * 64, wc = (w & 1) * 64;
  const int g = l >> 4, lane16 = l & 15;

  const int srow = tid >> 2;
  const int scol = (tid & 3) * 8;
  const unsigned short* Ag0 = A + (size_t)(m0 + srow) * F_SZ + scol + k0base;
  const unsigned short* Ag1 = A + (size_t)(m0 + 64 + srow) * F_SZ + scol + k0base;
  const unsigned short* Bg0 = Bm + (size_t)(n0 + srow) * F_SZ + scol + k0base;
  const unsigned short* Bg1 = Bm + (size_t)(n0 + 64 + srow) * F_SZ + scol + k0base;
  unsigned short* la0 = &lsA[tid * 8];
  unsigned short* la1 = &lsA[2048 + tid * 8];
  unsigned short* lb0 = &lsB[tid * 8];
  unsigned short* lb1 = &lsB[2048 + tid * 8];

  int ar[4], br[4];
#pragma unroll
  for (int m = 0; m < 4; ++m) ar[m] = (wr + m * 16 + lane16) * 32 + g * 8;
#pragma unroll
  for (int n = 0; n < 4; ++n) br[n] = (wc + n * 16 + lane16) * 32 + g * 8;

  f32x4 acc[4][4] = {};

  for (int k0 = 0; k0 < 1024; k0 += 32) {
    GLOAD16(Ag0 + k0, la0);
    GLOAD16(Ag1 + k0, la1);
    GLOAD16(Bg0 + k0, lb0);
    GLOAD16(Bg1 + k0, lb1);
    __syncthreads();
    bf16x8 af[4], bfv[4];
#pragma unroll
    for (int m = 0; m < 4; ++m) af[m] = *(const bf16x8*)&lsA[ar[m]];
#pragma unroll
    for (int n = 0; n < 4; ++n) bfv[n] = *(const bf16x8*)&lsB[br[n]];
#pragma unroll
    for (int m = 0; m < 4; ++m)
#pragma unroll
      for (int n = 0; n < 4; ++n)
        acc[m][n] = __builtin_amdgcn_mfma_f32_16x16x32_bf16(af[m], bfv[n], acc[m][n], 0, 0, 0);
    __syncthreads();
  }
#pragma unroll
  for (int m = 0; m < 4; ++m)
#pragma unroll
    for (int n = 0; n < 4; ++n)
#pragma unroll
      for (int r = 0; r < 4; ++r) {
        int row = m0 + wr + m * 16 + g * 4 + r;
        int col = n0 + wc + n * 16 + lane16;
        atomicAdd(&embf[(size_t)row * D_SZ + col], acc[m][n][r]);
      }
}

// embf f32 -> emb bf16 + per-row esq
__global__ __launch_bounds__(256) void esq_conv_k(const float* __restrict__ embf,
                                                  unsigned short* __restrict__ emb,
                                                  float* __restrict__ esq) {
  int r = blockIdx.x * 4 + (threadIdx.x >> 6);
  int t = threadIdx.x & 63;
  const float4* row = (const float4*)(embf + (size_t)r * D_SZ);
  float4 a = row[t * 2], b = row[t * 2 + 1];
  float v[8] = {a.x, a.y, a.z, a.w, b.x, b.y, b.z, b.w};
  ushort8 o;
  float s = 0.f;
#pragma unroll
  for (int j = 0; j < 8; ++j) {
    o[j] = f2bf(v[j]);
    float q = bf2f(o[j]);
    s += q * q;
  }
  *(ushort8*)&emb[(size_t)r * D_SZ + t * 8] = o;
#pragma unroll
  for (int off = 1; off < 64; off <<= 1) s += __shfl_xor(s, off);
  if (t == 0) esq[r] = s;
}

// ---------------- GEMM-B: persistent fused cdist-min, 256x256, 8-phase (m201 port) ------
// grid 256 (1 block/CU), 512 threads = 8 waves (2M x 4N), wave tile 128x64.
// mt = bid>>5 (8 M-tiles of 256); grp = bid&31: the 8 blocks sharing a B-stream have
// bid == grp (mod 8) -> SAME XCD, co-start -> one B fetch per XCD L2.
// LDS: 4-ring x (A 16KB + B 16KB) = 128KB. Each K-32 step = 4 fine phases (m201's
// 8-per-K-64 density): {2-6 ds_reads | 1 global_load_lds -> barrier -> lgkmcnt(0) ->
// 8-MFMA setprio cluster -> barrier}. Counted VMCNT(8) once per step (retire tile t+1;
// t+2,t+3 = 8 loads in flight). Loads retire in order, all threads issue identical
// load sequences -> counted wait + barrier race-free. No atomics: per-row min folded
// in registers across nt, one store per (grp,row).
__global__ __launch_bounds__(512, 2) void gemm_min_k(
    const unsigned short* __restrict__ A,   // emb [2048][512] bf16
    const unsigned short* __restrict__ Bm,  // lb  [100096][512] bf16
    const float* __restrict__ esq, const float* __restrict__ lsq,
    float* __restrict__ minpart) {          // [NGRP][2048]
  __shared__ unsigned short lsA[4 * 8192];  // 4 bufs x 256 rows x 32 k
  __shared__ unsigned short lsB[4 * 8192];

  const int tid = threadIdx.x;
  const int grp = blockIdx.x & 31;
  const int mt = blockIdx.x >> 5;      // 0..7
  const int m0 = mt * 256;
  const int J = (NTILES - grp + NGRP - 1) / NGRP;  // 12 or 13 nt-tiles
  const int T = J * 16;                            // total K-steps (BK=32)

  const int l = tid & 63;
  const int wid = tid >> 6;
  const int wm = wid >> 2;      // 0..1 -> rows wm*128
  const int wn = wid & 3;       // 0..3 -> cols wn*64
  const int g = l >> 4, lane16 = l & 15;

  // staging: linear LDS dest; source column slot pre-swizzled so ds_read's
  // slot' = slot ^ ((row>>1)&3) matches (both-sides-or-neither rule).
  const int srow = tid >> 2;                       // 0..127
  const int sslot = (tid & 3) ^ ((tid >> 3) & 3);
  const unsigned short* Ag0 = A + (size_t)(m0 + srow) * D_SZ + sslot * 8;
  const unsigned short* Ag1 = A + (size_t)(m0 + 128 + srow) * D_SZ + sslot * 8;
  const unsigned short* Bgs = Bm + (size_t)srow * D_SZ + sslot * 8;

  int ar[8], br[4];
#pragma unroll
  for (int m = 0; m < 8; ++m) {
    int row = wm * 128 + m * 16 + lane16;
    ar[m] = row * 32 + ((g ^ ((row >> 1) & 3)) * 8);
  }
#pragma unroll
  for (int n = 0; n < 4; ++n) {
    int row = wn * 64 + n * 16 + lane16;
    br[n] = row * 32 + ((g ^ ((row >> 1) & 3)) * 8);
  }

  f32x4 acc[8][4] = {};
  float rmin[8][4];
#pragma unroll
  for (int m = 0; m < 8; ++m)
#pragma unroll
    for (int r = 0; r < 4; ++r) rmin[m][r] = 3.0e38f;

  auto stage_all = [&](int s) {  // prologue only
    const int kt = (s & 15) * 32;
    const int b = s & 3;
    const size_t nrow = (size_t)(grp + NGRP * (s >> 4)) * 256 * D_SZ;
    GLOAD16(Ag0 + kt, &lsA[b * 8192 + tid * 8]);
    GLOAD16(Ag1 + kt, &lsA[b * 8192 + 4096 + tid * 8]);
    GLOAD16(Bgs + nrow + kt, &lsB[b * 8192 + tid * 8]);
    GLOAD16(Bgs + nrow + (size_t)128 * D_SZ + kt, &lsB[b * 8192 + 4096 + tid * 8]);
  };

  // prologue: tiles 0,1,2 in flight (12 loads); retire tile 0
  stage_all(0); stage_all(1); stage_all(2);
  VMCNT(8);
  BARRIER;

  for (int t = 0; t < T; ++t) {
    const int b = t & 3;
    const unsigned short* pA = &lsA[b * 8192];
    const unsigned short* pB = &lsB[b * 8192];
    const int s = t + 3;
    const bool stg = s < T;
    const int sb = s & 3;
    const int skt = (s & 15) * 32;
    const size_t snrow = (size_t)(grp + NGRP * (s >> 4)) * 256 * D_SZ;
    bf16x8 bfv[4], afa, afb;

    // ---- phase 0: bfv[0..3] + af[0..1] | stage A-lo | 8 MFMA (m0,m1) ----
#pragma unroll
    for (int n = 0; n < 4; ++n) bfv[n] = *(const bf16x8*)&pB[br[n]];
    afa = *(const bf16x8*)&pA[ar[0]];
    afb = *(const bf16x8*)&pA[ar[1]];
    if (stg) GLOAD16(Ag0 + skt, &lsA[sb * 8192 + tid * 8]);
    BARRIER; LGKM0;
    __builtin_amdgcn_s_setprio(1);
#pragma unroll
    for (int n = 0; n < 4; ++n)
      acc[0][n] = __builtin_amdgcn_mfma_f32_16x16x32_bf16(afa, bfv[n], acc[0][n], 0, 0, 0);
#pragma unroll
    for (int n = 0; n < 4; ++n)
      acc[1][n] = __builtin_amdgcn_mfma_f32_16x16x32_bf16(afb, bfv[n], acc[1][n], 0, 0, 0);
    __builtin_amdgcn_s_setprio(0);
    BARRIER;

    // ---- phase 1: af[2..3] | stage A-hi | 8 MFMA (m2,m3) ----
    afa = *(const bf16x8*)&pA[ar[2]];
    afb = *(const bf16x8*)&pA[ar[3]];
    if (stg) GLOAD16(Ag1 + skt, &lsA[sb * 8192 + 4096 + tid * 8]);
    BARRIER; LGKM0;
    __builtin_amdgcn_s_setprio(1);
#pragma unroll
    for (int n = 0; n < 4; ++n)
      acc[2][n] = __builtin_amdgcn_mfma_f32_16x16x32_bf16(afa, bfv[n], acc[2][n], 0, 0, 0);
#pragma unroll
    for (int n = 0; n < 4; ++n)
      acc[3][n] = __builtin_amdgcn_mfma_f32_16x16x32_bf16(afb, bfv[n], acc[3][n], 0, 0, 0);
    __builtin_amdgcn_s_setprio(0);
    BARRIER;

    // ---- phase 2: af[4..5] | stage B-lo | 8 MFMA (m4,m5) ----
    afa = *(const bf16x8*)&pA[ar[4]];
    afb = *(const bf16x8*)&pA[ar[5]];
    if (stg) GLOAD16(Bgs + snrow + skt, &lsB[sb * 8192 + tid * 8]);
    BARRIER; LGKM0;
    __builtin_amdgcn_s_setprio(1);
#pragma unroll
    for (int n = 0; n < 4; ++n)
      acc[4][n] = __builtin_amdgcn_mfma_f32_16x16x32_bf16(afa, bfv[n], acc[4][n], 0, 0, 0);
#pragma unroll
    for (int n = 0; n < 4; ++n)
      acc[5][n] = __builtin_amdgcn_mfma_f32_16x16x32_bf16(afb, bfv[n], acc[5][n], 0, 0, 0);
    __builtin_amdgcn_s_setprio(0);
    BARRIER;

    // ---- phase 3: af[6..7] | stage B-hi | 8 MFMA (m6,m7) | fold | vmcnt ----
    afa = *(const bf16x8*)&pA[ar[6]];
    afb = *(const bf16x8*)&pA[ar[7]];
    if (stg) GLOAD16(Bgs + snrow + (size_t)128 * D_SZ + skt, &lsB[sb * 8192 + 4096 + tid * 8]);
    BARRIER; LGKM0;
    __builtin_amdgcn_s_setprio(1);
#pragma unroll
    for (int n = 0; n < 4; ++n)
      acc[6][n] = __builtin_amdgcn_mfma_f32_16x16x32_bf16(afa, bfv[n], acc[6][n], 0, 0, 0);
#pragma unroll
    for (int n = 0; n < 4; ++n)
      acc[7][n] = __builtin_amdgcn_mfma_f32_16x16x32_bf16(afb, bfv[n], acc[7][n], 0, 0, 0);
    __builtin_amdgcn_s_setprio(0);

    if ((t & 15) == 15) {            // nt-tile boundary: fold min, reset acc (uniform)
      const int j = t >> 4;
      const int n0s = (grp + NGRP * j) * 256;
      float lsql[4];
#pragma unroll
      for (int n = 0; n < 4; ++n) lsql[n] = lsq[n0s + wn * 64 + n * 16 + lane16];
#pragma unroll
      for (int m = 0; m < 8; ++m)
#pragma unroll
        for (int r = 0; r < 4; ++r) {
          float v = fminf(fminf(lsql[0] - 2.0f * acc[m][0][r], lsql[1] - 2.0f * acc[m][1][r]),
                          fminf(lsql[2] - 2.0f * acc[m][2][r], lsql[3] - 2.0f * acc[m][3][r]));
          rmin[m][r] = fminf(rmin[m][r], v);
        }
#pragma unroll
      for (int m = 0; m < 8; ++m)
#pragma unroll
        for (int n = 0; n < 4; ++n) acc[m][n] = f32x4{0.f, 0.f, 0.f, 0.f};
    }

    if (stg)            { VMCNT(8); }   // retire tile t+1; t+2,t+3 in flight
    else if (t + 2 < T) { VMCNT(4); }   // t==T-3: retire T-2; T-1 in flight
    else if (t + 1 < T) { VMCNT(0); }   // t==T-2: final drain
    BARRIER;                            // publish tile t+1
  }

  // writeout: reduce rmin over the 16-lane col group, one store per (grp,row)
#pragma unroll
  for (int m = 0; m < 8; ++m)
#pragma unroll
    for (int r = 0; r < 4; ++r) {
      float best = rmin[m][r];
#pragma unroll
      for (int off = 1; off < 16; off <<= 1) best = fminf(best, __shfl_xor(best, off));
      if (lane16 == 0) {
        int row = m0 + wm * 128 + m * 16 + g * 4 + r;
        minpart[grp * B_SZ + row] = fmaxf(esq[row] + best, 0.0f);
      }
    }
}

// ---------------- final reductions ----------------

__global__ __launch_bounds__(256) void mse_final_k(const float* __restrict__ part,
                                                   float* __restrict__ msev,
                                                   int nparts, float inv_n) {
  float s = 0.f;
  for (int i = threadIdx.x; i < nparts; i += 256) s += part[i];
#pragma unroll
  for (int off = 1; off < 64; off <<= 1) s += __shfl_xor(s, off);
  __shared__ float sm[4];
  if ((threadIdx.x & 63) == 0) sm[threadIdx.x >> 6] = s;
  __syncthreads();
  if (threadIdx.x == 0) msev[0] = (sm[0] + sm[1] + sm[2] + sm[3]) * inv_n;
}

__global__ void finalize_k(const float* __restrict__ minpart,
                           const float* __restrict__ msev,
                           float* __restrict__ out, int n) {
  int i = blockIdx.x * blockDim.x + threadIdx.x;
  if (i < n) {
    float m = 3.0e38f;
#pragma unroll 8
    for (int gp = 0; gp < NGRP; ++gp) m = fminf(m, minpart[gp * B_SZ + i]);
    out[i] = msev[0] + fminf(50.0f - sqrtf(m), 0.0f) * 5.0f;
  }
}

// ---------------- launch ----------------

extern "C" void kernel_launch(void* const* d_in, const int* in_sizes, int n_in,
                              void* d_out, int out_size, void* d_ws, size_t ws_size,
                              hipStream_t stream) {
  const float* x  = (const float*)d_in[0];
  const float* y  = (const float*)d_in[1];
  const float* W  = (const float*)d_in[2];
  const float* lk = (const float*)d_in[3];
  float* out = (float*)d_out;

  char* ws = (char*)d_ws;
  size_t off = 0;
  auto alloc = [&](size_t bytes) -> void* {
    void* p = ws + off;
    off = (off + bytes + 255) & ~(size_t)255;
    return p;
  };
  unsigned short* xb  = (unsigned short*)alloc((size_t)B_SZ * F_SZ * 2);   // 50.3 MB
  unsigned short* Wt  = (unsigned short*)alloc((size_t)D_SZ * F_SZ * 2);   // 12.6 MB
  unsigned short* lb  = (unsigned short*)alloc((size_t)N_PAD * D_SZ * 2);  // 102.5 MB
  float* lsq          = (float*)alloc((size_t)N_PAD * 4);
  float* embf         = (float*)alloc((size_t)B_SZ * D_SZ * 4);            // 4 MB
  unsigned short* emb = (unsigned short*)alloc((size_t)B_SZ * D_SZ * 2);
  float* esq          = (float*)alloc((size_t)B_SZ * 4);
  float* minpart      = (float*)alloc((size_t)NGRP * B_SZ * 4);            // 256 KB
  float* msep         = (float*)alloc(2048 * 4);
  float* msev         = (float*)alloc(256);
  (void)ws_size; (void)in_sizes; (void)n_in; (void)out_size;

  // merged prep: x->bf16 + mse partials | W transpose | lookup conv+sumsq | zero embf
  prep_k<<<PREP_TOTAL, 256, 0, stream>>>(x, y, xb, msep, W, Wt, lk, lb, lsq, embf);

  // emb(f32) = xb @ Wt^T via split-K=12 atomicAdd (768 blocks, 3/CU)
  gemm_a_sk<<<768, 256, 0, stream>>>(xb, Wt, embf);
  esq_conv_k<<<B_SZ / 4, 256, 0, stream>>>(embf, emb, esq);

  // persistent fused cdist-min, 256 blocks (1/CU), 8-phase schedule
  gemm_min_k<<<256, 512, 0, stream>>>(emb, lb, esq, lsq, minpart);

  mse_final_k<<<1, 256, 0, stream>>>(msep, msev, 2048, 1.0f / ((float)B_SZ * (float)F_SZ));
  finalize_k<<<(B_SZ + 255) / 256, 256, 0, stream>>>(minpart, msev, out, B_SZ);
}